// Round 3
// baseline (50.073 us; speedup 1.0000x reference)
//
#include <hip/hip_runtime.h>

#define HOMO_BOOST_THRD 0.5f
#define HOMO_LOSS_WEIGHT 100.0f
#define COS_EPS 1e-8f
#define D_FEAT 128
#define EPT 4            // edges per thread
#define EDGE_BLOCK 256

// ---- workspace layout (in d_ws) ----
// words [0 .. FLAG_WORDS)   : 2-bit-per-node membership (bit0=bkd, bit1=tgt)
// word  [FLAG_WORDS]        : done-counter for last-block reduction
// bytes [16384 ...)         : per-block partial sums (float)
#define FLAG_WORDS_MAX 4096  // supports up to 65536 nodes (N=50000 -> 3125 words)

// One block: build the packed flag table in LDS, write it out coalesced,
// and zero the done-counter. No separate memset dispatch needed.
__global__ void build_flags_kernel(const int* __restrict__ target_nodes, int n_tgt,
                                   const int* __restrict__ bkd_nodes, int n_bkd,
                                   unsigned int* __restrict__ flags_w, int nwords,
                                   unsigned int* __restrict__ counter) {
    __shared__ unsigned int s[FLAG_WORDS_MAX];
    for (int i = threadIdx.x; i < nwords; i += blockDim.x) s[i] = 0u;
    __syncthreads();
    for (int i = threadIdx.x; i < n_tgt; i += blockDim.x) {
        int node = target_nodes[i];
        atomicOr(&s[node >> 4], 2u << ((node & 15) * 2));   // tgt = bit1 of pair
    }
    for (int i = threadIdx.x; i < n_bkd; i += blockDim.x) {
        int node = bkd_nodes[i];
        atomicOr(&s[node >> 4], 1u << ((node & 15) * 2));   // bkd = bit0 of pair
    }
    __syncthreads();
    for (int i = threadIdx.x; i < nwords; i += blockDim.x) flags_w[i] = s[i];
    if (threadIdx.x == 0) *counter = 0u;
}

__device__ __forceinline__ float edge_term(const float* __restrict__ x, int u, int v) {
    const float4* xu = reinterpret_cast<const float4*>(x + (size_t)u * D_FEAT);
    const float4* xv = reinterpret_cast<const float4*>(x + (size_t)v * D_FEAT);
    float dot = 0.0f, nu2 = 0.0f, nv2 = 0.0f;
    #pragma unroll
    for (int k = 0; k < D_FEAT / 4; ++k) {
        float4 a = xu[k];
        float4 b = xv[k];
        dot += a.x * b.x + a.y * b.y + a.z * b.z + a.w * b.w;
        nu2 += a.x * a.x + a.y * a.y + a.z * a.z + a.w * a.w;
        nv2 += b.x * b.x + b.y * b.y + b.z * b.z + b.w * b.w;
    }
    float nu = fmaxf(sqrtf(nu2), COS_EPS);
    float nv = fmaxf(sqrtf(nv2), COS_EPS);
    return fmaxf(HOMO_BOOST_THRD - dot / (nu * nv), 0.0f);
}

__device__ __forceinline__ unsigned flag_of(const unsigned int* __restrict__ fw, int n) {
    return (fw[n >> 4] >> ((n & 15) * 2)) & 3u;
}

__global__ __launch_bounds__(EDGE_BLOCK) void edge_loss_kernel(
        const int* __restrict__ edge_index,        // [2*E]
        const float* __restrict__ edge_weights,    // [E]
        const float* __restrict__ x,               // [N,128]
        const unsigned int* __restrict__ flags_w,  // 2 bits/node, L1-resident
        float* __restrict__ partials,
        unsigned int* __restrict__ counter,
        float* __restrict__ out,
        int E, int nblocks) {
    __shared__ float wsum[EDGE_BLOCK / 64];
    __shared__ int is_last;

    int base = (blockIdx.x * EDGE_BLOCK + threadIdx.x) * EPT;
    float acc = 0.0f;

    if (((E & 3) == 0) && (base + EPT <= E)) {
        int4 uq = *reinterpret_cast<const int4*>(edge_index + base);
        int4 vq = *reinterpret_cast<const int4*>(edge_index + E + base);
        int us[EPT] = {uq.x, uq.y, uq.z, uq.w};
        int vs[EPT] = {vq.x, vq.y, vq.z, vq.w};
        #pragma unroll
        for (int k = 0; k < EPT; ++k) {
            unsigned fu = flag_of(flags_w, us[k]);
            unsigned fv = flag_of(flags_w, vs[k]);
            bool m = (((fu & (fv >> 1)) | (fv & (fu >> 1))) & 1u) != 0;
            if (m && edge_weights[base + k] != 0.0f)
                acc += edge_term(x, us[k], vs[k]);
        }
    } else {
        for (int k = 0; k < EPT; ++k) {
            int e = base + k;
            if (e >= E) break;
            int u = edge_index[e], v = edge_index[E + e];
            unsigned fu = flag_of(flags_w, u);
            unsigned fv = flag_of(flags_w, v);
            bool m = (((fu & (fv >> 1)) | (fv & (fu >> 1))) & 1u) != 0;
            if (m && edge_weights[e] != 0.0f)
                acc += edge_term(x, u, v);
        }
    }

    // wave (64-lane) + block reduction
    #pragma unroll
    for (int off = 32; off > 0; off >>= 1) acc += __shfl_down(acc, off, 64);
    if ((threadIdx.x & 63) == 0) wsum[threadIdx.x >> 6] = acc;
    __syncthreads();

    if (threadIdx.x == 0) {
        float b = wsum[0] + wsum[1] + wsum[2] + wsum[3];
        partials[blockIdx.x] = b;
        __threadfence();                               // release partials write
        unsigned old = atomicAdd(counter, 1u);
        is_last = (old == (unsigned)(nblocks - 1)) ? 1 : 0;
    }
    __syncthreads();

    if (is_last) {
        // device-scope atomic reads sidestep any stale-L2 concern across XCDs
        float s = 0.0f;
        for (int i = threadIdx.x; i < nblocks; i += EDGE_BLOCK)
            s += atomicAdd(&partials[i], 0.0f);
        #pragma unroll
        for (int off = 32; off > 0; off >>= 1) s += __shfl_down(s, off, 64);
        __syncthreads();
        if ((threadIdx.x & 63) == 0) wsum[threadIdx.x >> 6] = s;
        __syncthreads();
        if (threadIdx.x == 0)
            out[0] = (wsum[0] + wsum[1] + wsum[2] + wsum[3]) * HOMO_LOSS_WEIGHT;
    }
}

extern "C" void kernel_launch(void* const* d_in, const int* in_sizes, int n_in,
                              void* d_out, int out_size, void* d_ws, size_t ws_size,
                              hipStream_t stream) {
    const int*   edge_index   = (const int*)  d_in[0];
    const float* edge_weights = (const float*)d_in[1];
    const float* x            = (const float*)d_in[2];
    const int*   target_nodes = (const int*)  d_in[3];
    const int*   bkd_nodes    = (const int*)  d_in[4];

    const int E     = in_sizes[0] / 2;
    const int N     = in_sizes[2] / D_FEAT;
    const int n_tgt = in_sizes[3];
    const int n_bkd = in_sizes[4];

    const int nwords = (N + 15) / 16;                 // 2 bits per node
    unsigned int* flags_w = (unsigned int*)d_ws;
    unsigned int* counter = flags_w + FLAG_WORDS_MAX; // word right after flag region
    float* partials = (float*)((char*)d_ws + 32768);

    build_flags_kernel<<<1, 1024, 0, stream>>>(
        target_nodes, n_tgt, bkd_nodes, n_bkd, flags_w, nwords, counter);

    const int nblocks = (E + EDGE_BLOCK * EPT - 1) / (EDGE_BLOCK * EPT);
    edge_loss_kernel<<<nblocks, EDGE_BLOCK, 0, stream>>>(
        edge_index, edge_weights, x, flags_w, partials, counter,
        (float*)d_out, E, nblocks);
}

// Round 4
// 30.712 us; speedup vs baseline: 1.6304x; 1.6304x over previous
//
#include <hip/hip_runtime.h>

#define HOMO_BOOST_THRD 0.5f
#define HOMO_LOSS_WEIGHT 100.0f
#define COS_EPS 1e-8f
#define D_FEAT 128
#define EDGE_BLOCK 256

#define FLAG_WORDS_MAX 4096  // 2 bits/node -> supports up to 65536 nodes

// One block: build packed 2-bit membership table in LDS, write out coalesced.
// bit0 = bkd, bit1 = tgt.
__global__ void build_flags_kernel(const int* __restrict__ target_nodes, int n_tgt,
                                   const int* __restrict__ bkd_nodes, int n_bkd,
                                   unsigned int* __restrict__ flags_w, int nwords) {
    __shared__ unsigned int s[FLAG_WORDS_MAX];
    for (int i = threadIdx.x; i < nwords; i += blockDim.x) s[i] = 0u;
    __syncthreads();
    for (int i = threadIdx.x; i < n_tgt; i += blockDim.x) {
        int node = target_nodes[i];
        atomicOr(&s[node >> 4], 2u << ((node & 15) * 2));
    }
    for (int i = threadIdx.x; i < n_bkd; i += blockDim.x) {
        int node = bkd_nodes[i];
        atomicOr(&s[node >> 4], 1u << ((node & 15) * 2));
    }
    __syncthreads();
    for (int i = threadIdx.x; i < nwords; i += blockDim.x) flags_w[i] = s[i];
}

__device__ __forceinline__ float edge_term(const float* __restrict__ x, int u, int v) {
    const float4* xu = reinterpret_cast<const float4*>(x + (size_t)u * D_FEAT);
    const float4* xv = reinterpret_cast<const float4*>(x + (size_t)v * D_FEAT);
    float dot = 0.0f, nu2 = 0.0f, nv2 = 0.0f;
    #pragma unroll
    for (int k = 0; k < D_FEAT / 4; ++k) {
        float4 a = xu[k];
        float4 b = xv[k];
        dot += a.x * b.x + a.y * b.y + a.z * b.z + a.w * b.w;
        nu2 += a.x * a.x + a.y * a.y + a.z * a.z + a.w * a.w;
        nv2 += b.x * b.x + b.y * b.y + b.z * b.z + b.w * b.w;
    }
    float nu = fmaxf(sqrtf(nu2), COS_EPS);
    float nv = fmaxf(sqrtf(nv2), COS_EPS);
    return fmaxf(HOMO_BOOST_THRD - dot / (nu * nv), 0.0f);
}

// 1 edge per thread; per-wave shuffle reduce; lane0 stores to partials[wave].
// NO atomics, NO threadfence, NO __syncthreads in the hot path.
__global__ __launch_bounds__(EDGE_BLOCK) void edge_loss_kernel(
        const int* __restrict__ edge_index,        // [2*E]
        const float* __restrict__ edge_weights,    // [E]
        const float* __restrict__ x,               // [N,128]
        const unsigned int* __restrict__ flags_w,  // 2 bits/node, 12.5 KB
        float* __restrict__ partials, int E) {
    int e = blockIdx.x * EDGE_BLOCK + threadIdx.x;
    float val = 0.0f;
    if (e < E) {
        int u = edge_index[e];
        int v = edge_index[E + e];
        unsigned fu = (flags_w[u >> 4] >> ((u & 15) * 2)) & 3u;
        unsigned fv = (flags_w[v >> 4] >> ((v & 15) * 2)) & 3u;
        bool m = (((fu & (fv >> 1)) | (fv & (fu >> 1))) & 1u) != 0;
        if (m && edge_weights[e] != 0.0f)
            val = edge_term(x, u, v);
    }
    #pragma unroll
    for (int off = 32; off > 0; off >>= 1) val += __shfl_down(val, off, 64);
    if ((threadIdx.x & 63) == 0)
        partials[blockIdx.x * (EDGE_BLOCK / 64) + (threadIdx.x >> 6)] = val;
}

__global__ void reduce_kernel(const float* __restrict__ partials, int n,
                              float* __restrict__ out) {
    __shared__ float wsum[16];
    float s = 0.0f;
    for (int i = threadIdx.x; i < n; i += blockDim.x) s += partials[i];
    #pragma unroll
    for (int off = 32; off > 0; off >>= 1) s += __shfl_down(s, off, 64);
    if ((threadIdx.x & 63) == 0) wsum[threadIdx.x >> 6] = s;
    __syncthreads();
    if (threadIdx.x == 0) {
        float t = 0.0f;
        for (int w = 0; w < (int)(blockDim.x >> 6); ++w) t += wsum[w];
        out[0] = t * HOMO_LOSS_WEIGHT;
    }
}

extern "C" void kernel_launch(void* const* d_in, const int* in_sizes, int n_in,
                              void* d_out, int out_size, void* d_ws, size_t ws_size,
                              hipStream_t stream) {
    const int*   edge_index   = (const int*)  d_in[0];
    const float* edge_weights = (const float*)d_in[1];
    const float* x            = (const float*)d_in[2];
    const int*   target_nodes = (const int*)  d_in[3];
    const int*   bkd_nodes    = (const int*)  d_in[4];

    const int E     = in_sizes[0] / 2;
    const int N     = in_sizes[2] / D_FEAT;
    const int n_tgt = in_sizes[3];
    const int n_bkd = in_sizes[4];

    const int nwords = (N + 15) / 16;
    unsigned int* flags_w = (unsigned int*)d_ws;
    float* partials = (float*)((char*)d_ws + 32768);

    build_flags_kernel<<<1, 1024, 0, stream>>>(
        target_nodes, n_tgt, bkd_nodes, n_bkd, flags_w, nwords);

    const int nblocks = (E + EDGE_BLOCK - 1) / EDGE_BLOCK;
    const int nwaves  = nblocks * (EDGE_BLOCK / 64);
    edge_loss_kernel<<<nblocks, EDGE_BLOCK, 0, stream>>>(
        edge_index, edge_weights, x, flags_w, partials, E);

    reduce_kernel<<<1, 1024, 0, stream>>>(partials, nwaves, (float*)d_out);
}

// Round 5
// 26.980 us; speedup vs baseline: 1.8559x; 1.1383x over previous
//
#include <hip/hip_runtime.h>

#define HOMO_BOOST_THRD 0.5f
#define HOMO_LOSS_WEIGHT 100.0f
#define COS_EPS 1e-8f
#define D_FEAT 128
#define EDGE_BLOCK 256
#define EDGE_GRID 2048          // 8 blocks/CU on 256 CUs

#define FLAG_WORDS_MAX 4096     // 2 bits/node -> up to 65536 nodes (16 KB LDS)

// One block: build packed 2-bit membership table in LDS, write out coalesced.
// bit0 = bkd, bit1 = tgt.
__global__ void build_flags_kernel(const int* __restrict__ target_nodes, int n_tgt,
                                   const int* __restrict__ bkd_nodes, int n_bkd,
                                   unsigned int* __restrict__ flags_w, int nwords) {
    __shared__ unsigned int s[FLAG_WORDS_MAX];
    for (int i = threadIdx.x; i < nwords; i += blockDim.x) s[i] = 0u;
    __syncthreads();
    for (int i = threadIdx.x; i < n_tgt; i += blockDim.x) {
        int node = target_nodes[i];
        atomicOr(&s[node >> 4], 2u << ((node & 15) * 2));
    }
    for (int i = threadIdx.x; i < n_bkd; i += blockDim.x) {
        int node = bkd_nodes[i];
        atomicOr(&s[node >> 4], 1u << ((node & 15) * 2));
    }
    __syncthreads();
    for (int i = threadIdx.x; i < nwords; i += blockDim.x) flags_w[i] = s[i];
}

__device__ __forceinline__ float edge_term(const float* __restrict__ x, int u, int v) {
    const float4* xu = reinterpret_cast<const float4*>(x + (size_t)u * D_FEAT);
    const float4* xv = reinterpret_cast<const float4*>(x + (size_t)v * D_FEAT);
    float dot = 0.0f, nu2 = 0.0f, nv2 = 0.0f;
    #pragma unroll
    for (int k = 0; k < D_FEAT / 4; ++k) {
        float4 a = xu[k];
        float4 b = xv[k];
        dot += a.x * b.x + a.y * b.y + a.z * b.z + a.w * b.w;
        nu2 += a.x * a.x + a.y * a.y + a.z * a.z + a.w * a.w;
        nv2 += b.x * b.x + b.y * b.y + b.z * b.z + b.w * b.w;
    }
    float nu = fmaxf(sqrtf(nu2), COS_EPS);
    float nv = fmaxf(sqrtf(nv2), COS_EPS);
    return fmaxf(HOMO_BOOST_THRD - dot / (nu * nv), 0.0f);
}

// Grid-stride over edges; flag table staged in LDS (random gathers hit LDS,
// not the L1 texture path). No atomics/fences in the hot path.
__global__ __launch_bounds__(EDGE_BLOCK) void edge_loss_kernel(
        const int* __restrict__ edge_index,        // [2*E]
        const float* __restrict__ edge_weights,    // [E]
        const float* __restrict__ x,               // [N,128]
        const unsigned int* __restrict__ flags_w,  // 2 bits/node
        float* __restrict__ partials, int E, int nwords) {
    __shared__ unsigned int sflags[FLAG_WORDS_MAX];
    for (int i = threadIdx.x; i < nwords; i += EDGE_BLOCK) sflags[i] = flags_w[i];
    __syncthreads();

    const int stride = gridDim.x * EDGE_BLOCK;
    float val = 0.0f;
    for (int e = blockIdx.x * EDGE_BLOCK + threadIdx.x; e < E; e += stride) {
        int u = edge_index[e];
        int v = edge_index[E + e];
        unsigned fu = (sflags[u >> 4] >> ((u & 15) * 2)) & 3u;
        unsigned fv = (sflags[v >> 4] >> ((v & 15) * 2)) & 3u;
        bool m = (((fu & (fv >> 1)) | (fv & (fu >> 1))) & 1u) != 0;
        if (m && edge_weights[e] != 0.0f)
            val += edge_term(x, u, v);
    }

    #pragma unroll
    for (int off = 32; off > 0; off >>= 1) val += __shfl_down(val, off, 64);
    if ((threadIdx.x & 63) == 0)
        partials[blockIdx.x * (EDGE_BLOCK / 64) + (threadIdx.x >> 6)] = val;
}

// Single block; partials count is fixed (EDGE_GRID * 4 waves) and % 4 == 0.
__global__ void reduce_kernel(const float* __restrict__ partials, int n4,
                              float* __restrict__ out) {
    __shared__ float wsum[16];
    const float4* p4 = reinterpret_cast<const float4*>(partials);
    float s = 0.0f;
    for (int i = threadIdx.x; i < n4; i += blockDim.x) {
        float4 v = p4[i];
        s += v.x + v.y + v.z + v.w;
    }
    #pragma unroll
    for (int off = 32; off > 0; off >>= 1) s += __shfl_down(s, off, 64);
    if ((threadIdx.x & 63) == 0) wsum[threadIdx.x >> 6] = s;
    __syncthreads();
    if (threadIdx.x == 0) {
        float t = 0.0f;
        for (int w = 0; w < (int)(blockDim.x >> 6); ++w) t += wsum[w];
        out[0] = t * HOMO_LOSS_WEIGHT;
    }
}

extern "C" void kernel_launch(void* const* d_in, const int* in_sizes, int n_in,
                              void* d_out, int out_size, void* d_ws, size_t ws_size,
                              hipStream_t stream) {
    const int*   edge_index   = (const int*)  d_in[0];
    const float* edge_weights = (const float*)d_in[1];
    const float* x            = (const float*)d_in[2];
    const int*   target_nodes = (const int*)  d_in[3];
    const int*   bkd_nodes    = (const int*)  d_in[4];

    const int E     = in_sizes[0] / 2;
    const int N     = in_sizes[2] / D_FEAT;
    const int n_tgt = in_sizes[3];
    const int n_bkd = in_sizes[4];

    const int nwords = (N + 15) / 16;
    unsigned int* flags_w = (unsigned int*)d_ws;
    float* partials = (float*)((char*)d_ws + 32768);

    build_flags_kernel<<<1, 1024, 0, stream>>>(
        target_nodes, n_tgt, bkd_nodes, n_bkd, flags_w, nwords);

    edge_loss_kernel<<<EDGE_GRID, EDGE_BLOCK, 0, stream>>>(
        edge_index, edge_weights, x, flags_w, partials, E, nwords);

    const int nwaves = EDGE_GRID * (EDGE_BLOCK / 64);
    reduce_kernel<<<1, 1024, 0, stream>>>(partials, nwaves / 4, (float*)d_out);
}

// Round 6
// 25.505 us; speedup vs baseline: 1.9633x; 1.0579x over previous
//
#include <hip/hip_runtime.h>

#define HOMO_BOOST_THRD 0.5f
#define HOMO_LOSS_WEIGHT 100.0f
#define COS_EPS 1e-8f
#define D_FEAT 128
#define EDGE_BLOCK 256
#define EPT 4

#define FLAG_WORDS_MAX 4096     // 2 bits/node -> up to 65536 nodes (16 KB LDS)

__device__ __forceinline__ float edge_term(const float* __restrict__ x, int u, int v) {
    const float4* xu = reinterpret_cast<const float4*>(x + (size_t)u * D_FEAT);
    const float4* xv = reinterpret_cast<const float4*>(x + (size_t)v * D_FEAT);
    float dot = 0.0f, nu2 = 0.0f, nv2 = 0.0f;
    #pragma unroll
    for (int k = 0; k < D_FEAT / 4; ++k) {
        float4 a = xu[k];
        float4 b = xv[k];
        dot += a.x * b.x + a.y * b.y + a.z * b.z + a.w * b.w;
        nu2 += a.x * a.x + a.y * a.y + a.z * a.z + a.w * a.w;
        nv2 += b.x * b.x + b.y * b.y + b.z * b.z + b.w * b.w;
    }
    float nu = fmaxf(sqrtf(nu2), COS_EPS);
    float nv = fmaxf(sqrtf(nv2), COS_EPS);
    return fmaxf(HOMO_BOOST_THRD - dot / (nu * nv), 0.0f);
}

// Each block builds its own LDS flag table (no serial prep dispatch), then
// processes 4 edges/thread with int4 loads. bit0 = bkd, bit1 = tgt.
// No atomics/fences on global memory in the hot path.
__global__ __launch_bounds__(EDGE_BLOCK) void edge_loss_kernel(
        const int* __restrict__ edge_index,        // [2*E]
        const float* __restrict__ edge_weights,    // [E]
        const float* __restrict__ x,               // [N,128]
        const int* __restrict__ target_nodes, int n_tgt,
        const int* __restrict__ bkd_nodes, int n_bkd,
        float* __restrict__ partials, int E, int nwords) {
    __shared__ unsigned int sflags[FLAG_WORDS_MAX];
    for (int i = threadIdx.x; i < nwords; i += EDGE_BLOCK) sflags[i] = 0u;
    __syncthreads();
    for (int i = threadIdx.x; i < n_tgt; i += EDGE_BLOCK) {
        int node = target_nodes[i];
        atomicOr(&sflags[node >> 4], 2u << ((node & 15) * 2));
    }
    for (int i = threadIdx.x; i < n_bkd; i += EDGE_BLOCK) {
        int node = bkd_nodes[i];
        atomicOr(&sflags[node >> 4], 1u << ((node & 15) * 2));
    }
    __syncthreads();

    const int base = (blockIdx.x * EDGE_BLOCK + threadIdx.x) * EPT;
    float val = 0.0f;

    if (((E & 3) == 0) && (base + EPT <= E)) {
        // both rows 16B-aligned when E % 4 == 0
        int4 uq = *reinterpret_cast<const int4*>(edge_index + base);
        int4 vq = *reinterpret_cast<const int4*>(edge_index + E + base);
        int us[EPT] = {uq.x, uq.y, uq.z, uq.w};
        int vs[EPT] = {vq.x, vq.y, vq.z, vq.w};
        #pragma unroll
        for (int k = 0; k < EPT; ++k) {
            unsigned fu = (sflags[us[k] >> 4] >> ((us[k] & 15) * 2)) & 3u;
            unsigned fv = (sflags[vs[k] >> 4] >> ((vs[k] & 15) * 2)) & 3u;
            bool m = (((fu & (fv >> 1)) | (fv & (fu >> 1))) & 1u) != 0;
            if (m && edge_weights[base + k] != 0.0f)
                val += edge_term(x, us[k], vs[k]);
        }
    } else {
        for (int k = 0; k < EPT; ++k) {
            int e = base + k;
            if (e >= E) break;
            int u = edge_index[e], v = edge_index[E + e];
            unsigned fu = (sflags[u >> 4] >> ((u & 15) * 2)) & 3u;
            unsigned fv = (sflags[v >> 4] >> ((v & 15) * 2)) & 3u;
            bool m = (((fu & (fv >> 1)) | (fv & (fu >> 1))) & 1u) != 0;
            if (m && edge_weights[e] != 0.0f)
                val += edge_term(x, u, v);
        }
    }

    #pragma unroll
    for (int off = 32; off > 0; off >>= 1) val += __shfl_down(val, off, 64);
    if ((threadIdx.x & 63) == 0)
        partials[blockIdx.x * (EDGE_BLOCK / 64) + (threadIdx.x >> 6)] = val;
}

__global__ void reduce_kernel(const float* __restrict__ partials, int n,
                              float* __restrict__ out) {
    __shared__ float wsum[16];
    float s = 0.0f;
    for (int i = threadIdx.x; i < n; i += blockDim.x) s += partials[i];
    #pragma unroll
    for (int off = 32; off > 0; off >>= 1) s += __shfl_down(s, off, 64);
    if ((threadIdx.x & 63) == 0) wsum[threadIdx.x >> 6] = s;
    __syncthreads();
    if (threadIdx.x == 0) {
        float t = 0.0f;
        for (int w = 0; w < (int)(blockDim.x >> 6); ++w) t += wsum[w];
        out[0] = t * HOMO_LOSS_WEIGHT;
    }
}

extern "C" void kernel_launch(void* const* d_in, const int* in_sizes, int n_in,
                              void* d_out, int out_size, void* d_ws, size_t ws_size,
                              hipStream_t stream) {
    const int*   edge_index   = (const int*)  d_in[0];
    const float* edge_weights = (const float*)d_in[1];
    const float* x            = (const float*)d_in[2];
    const int*   target_nodes = (const int*)  d_in[3];
    const int*   bkd_nodes    = (const int*)  d_in[4];

    const int E     = in_sizes[0] / 2;
    const int N     = in_sizes[2] / D_FEAT;
    const int n_tgt = in_sizes[3];
    const int n_bkd = in_sizes[4];

    const int nwords = (N + 15) / 16;
    float* partials = (float*)d_ws;

    const int nblocks = (E + EDGE_BLOCK * EPT - 1) / (EDGE_BLOCK * EPT);
    edge_loss_kernel<<<nblocks, EDGE_BLOCK, 0, stream>>>(
        edge_index, edge_weights, x, target_nodes, n_tgt, bkd_nodes, n_bkd,
        partials, E, nwords);

    const int nwaves = nblocks * (EDGE_BLOCK / 64);
    reduce_kernel<<<1, 1024, 0, stream>>>(partials, nwaves, (float*)d_out);
}

// Round 7
// 16.238 us; speedup vs baseline: 3.0837x; 1.5707x over previous
//
#include <hip/hip_runtime.h>

#define HOMO_BOOST_THRD 0.5f
#define HOMO_LOSS_WEIGHT 100.0f
#define COS_EPS 1e-8f
#define D_FEAT 128
#define EDGE_BLOCK 256
#define EPT 4

#define FLAG_WORDS_MAX 4096     // 2 bits/node -> up to 65536 nodes (16 KB LDS)

// Each block builds its own packed 2-bit LDS flag table (bit0=bkd, bit1=tgt),
// scans EPT edges/thread with int4 loads, and processes the rare matched
// edges WAVE-COOPERATIVELY (whole row per wave, butterfly reduce).
// No global atomics/fences anywhere in the hot path.
__global__ __launch_bounds__(EDGE_BLOCK) void edge_loss_kernel(
        const int* __restrict__ edge_index,        // [2*E]
        const float* __restrict__ edge_weights,    // [E]
        const float* __restrict__ x,               // [N,128]
        const int* __restrict__ target_nodes, int n_tgt,
        const int* __restrict__ bkd_nodes, int n_bkd,
        float* __restrict__ partials, int E, int nwords) {
    __shared__ unsigned int sflags[FLAG_WORDS_MAX];
    for (int i = threadIdx.x; i < nwords; i += EDGE_BLOCK) sflags[i] = 0u;
    __syncthreads();
    for (int i = threadIdx.x; i < n_tgt; i += EDGE_BLOCK) {
        int node = target_nodes[i];
        atomicOr(&sflags[node >> 4], 2u << ((node & 15) * 2));
    }
    for (int i = threadIdx.x; i < n_bkd; i += EDGE_BLOCK) {
        int node = bkd_nodes[i];
        atomicOr(&sflags[node >> 4], 1u << ((node & 15) * 2));
    }
    __syncthreads();

    const int lane = threadIdx.x & 63;
    const int base = (blockIdx.x * EDGE_BLOCK + threadIdx.x) * EPT;      // this lane's 1st edge
    const int wave_base = (blockIdx.x * EDGE_BLOCK + (threadIdx.x & ~63)) * EPT; // wave's 1st edge
    const bool wave_full = (wave_base + 64 * EPT <= E);

    int us[EPT], vs[EPT];
    if (wave_full) {
        int4 uq = *reinterpret_cast<const int4*>(edge_index + base);
        int4 vq = *reinterpret_cast<const int4*>(edge_index + E + base);
        us[0] = uq.x; us[1] = uq.y; us[2] = uq.z; us[3] = uq.w;
        vs[0] = vq.x; vs[1] = vq.y; vs[2] = vq.z; vs[3] = vq.w;
    } else {
        #pragma unroll
        for (int k = 0; k < EPT; ++k) {
            int e = base + k;
            bool ok = (e < E);
            us[k] = ok ? edge_index[e] : 0;
            vs[k] = ok ? edge_index[E + e] : 0;
        }
    }

    float wval = 0.0f;   // accumulated on lane 0 only

    #pragma unroll
    for (int k = 0; k < EPT; ++k) {
        bool valid = wave_full || (base + k < E);
        unsigned fu = (sflags[us[k] >> 4] >> ((us[k] & 15) * 2)) & 3u;
        unsigned fv = (sflags[vs[k] >> 4] >> ((vs[k] & 15) * 2)) & 3u;
        bool m = valid && ((((fu & (fv >> 1)) | (fv & (fu >> 1))) & 1u) != 0);

        unsigned long long mb = __ballot(m);
        while (mb) {
            int b = __ffsll(mb) - 1;
            mb &= mb - 1;
            int eu = __shfl(us[k], b, 64);
            int ev = __shfl(vs[k], b, 64);
            int e_b = wave_base + b * EPT + k;
            float w = edge_weights[e_b];          // uniform address -> broadcast
            if (w != 0.0f) {
                // whole wave loads both rows: lane l takes dims 2l, 2l+1
                float2 a = reinterpret_cast<const float2*>(x + (size_t)eu * D_FEAT)[lane];
                float2 c = reinterpret_cast<const float2*>(x + (size_t)ev * D_FEAT)[lane];
                float d  = a.x * c.x + a.y * c.y;
                float p  = a.x * a.x + a.y * a.y;
                float q  = c.x * c.x + c.y * c.y;
                #pragma unroll
                for (int off = 1; off < 64; off <<= 1) {
                    d += __shfl_xor(d, off, 64);
                    p += __shfl_xor(p, off, 64);
                    q += __shfl_xor(q, off, 64);
                }
                float nu = fmaxf(sqrtf(p), COS_EPS);
                float nv = fmaxf(sqrtf(q), COS_EPS);
                float term = fmaxf(HOMO_BOOST_THRD - d / (nu * nv), 0.0f);
                if (lane == 0) wval += term;
            }
        }
    }

    if (lane == 0)
        partials[blockIdx.x * (EDGE_BLOCK / 64) + (threadIdx.x >> 6)] = wval;
}

__global__ void reduce_kernel(const float* __restrict__ partials, int n,
                              float* __restrict__ out) {
    __shared__ float wsum[16];
    float s = 0.0f;
    for (int i = threadIdx.x; i < n; i += blockDim.x) s += partials[i];
    #pragma unroll
    for (int off = 32; off > 0; off >>= 1) s += __shfl_down(s, off, 64);
    if ((threadIdx.x & 63) == 0) wsum[threadIdx.x >> 6] = s;
    __syncthreads();
    if (threadIdx.x == 0) {
        float t = 0.0f;
        for (int w = 0; w < (int)(blockDim.x >> 6); ++w) t += wsum[w];
        out[0] = t * HOMO_LOSS_WEIGHT;
    }
}

extern "C" void kernel_launch(void* const* d_in, const int* in_sizes, int n_in,
                              void* d_out, int out_size, void* d_ws, size_t ws_size,
                              hipStream_t stream) {
    const int*   edge_index   = (const int*)  d_in[0];
    const float* edge_weights = (const float*)d_in[1];
    const float* x            = (const float*)d_in[2];
    const int*   target_nodes = (const int*)  d_in[3];
    const int*   bkd_nodes    = (const int*)  d_in[4];

    const int E     = in_sizes[0] / 2;
    const int N     = in_sizes[2] / D_FEAT;
    const int n_tgt = in_sizes[3];
    const int n_bkd = in_sizes[4];

    const int nwords = (N + 15) / 16;
    float* partials = (float*)d_ws;

    const int nblocks = (E + EDGE_BLOCK * EPT - 1) / (EDGE_BLOCK * EPT);
    edge_loss_kernel<<<nblocks, EDGE_BLOCK, 0, stream>>>(
        edge_index, edge_weights, x, target_nodes, n_tgt, bkd_nodes, n_bkd,
        partials, E, nwords);

    const int nwaves = nblocks * (EDGE_BLOCK / 64);
    reduce_kernel<<<1, 1024, 0, stream>>>(partials, nwaves, (float*)d_out);
}

// Round 8
// 14.923 us; speedup vs baseline: 3.3554x; 1.0881x over previous
//
#include <hip/hip_runtime.h>

#define HOMO_BOOST_THRD 0.5f
#define HOMO_LOSS_WEIGHT 100.0f
#define COS_EPS 1e-8f
#define D_FEAT 128
#define EDGE_BLOCK 256
#define EPT 8

#define FLAG_WORDS_MAX 4096     // 2 bits/node -> up to 65536 nodes (16 KB LDS)

// Single hot kernel: per-block packed 2-bit LDS flag table (bit0=bkd, bit1=tgt)
// built with vectorized loads/stores, EPT edges/thread scan with int4 loads,
// rare matched edges processed wave-cooperatively (whole row, butterfly).
// No global atomics/fences anywhere.
__global__ __launch_bounds__(EDGE_BLOCK) void edge_loss_kernel(
        const int* __restrict__ edge_index,        // [2*E]
        const float* __restrict__ edge_weights,    // [E]
        const float* __restrict__ x,               // [N,128]
        const int* __restrict__ target_nodes, int n_tgt,
        const int* __restrict__ bkd_nodes, int n_bkd,
        float* __restrict__ partials, int E, int nwords) {
    __shared__ unsigned int sflags[FLAG_WORDS_MAX];

    // ---- prologue: build flag table (vectorized) ----
    uint4* s4 = reinterpret_cast<uint4*>(sflags);
    const int nwords4 = (nwords + 3) >> 2;
    for (int i = threadIdx.x; i < nwords4; i += EDGE_BLOCK)
        s4[i] = make_uint4(0u, 0u, 0u, 0u);
    __syncthreads();

    const int n_tgt4 = n_tgt >> 2;
    const int4* t4 = reinterpret_cast<const int4*>(target_nodes);
    for (int i = threadIdx.x; i < n_tgt4; i += EDGE_BLOCK) {
        int4 nd = t4[i];
        atomicOr(&sflags[nd.x >> 4], 2u << ((nd.x & 15) * 2));
        atomicOr(&sflags[nd.y >> 4], 2u << ((nd.y & 15) * 2));
        atomicOr(&sflags[nd.z >> 4], 2u << ((nd.z & 15) * 2));
        atomicOr(&sflags[nd.w >> 4], 2u << ((nd.w & 15) * 2));
    }
    for (int i = (n_tgt4 << 2) + threadIdx.x; i < n_tgt; i += EDGE_BLOCK) {
        int node = target_nodes[i];
        atomicOr(&sflags[node >> 4], 2u << ((node & 15) * 2));
    }
    const int n_bkd4 = n_bkd >> 2;
    const int4* b4 = reinterpret_cast<const int4*>(bkd_nodes);
    for (int i = threadIdx.x; i < n_bkd4; i += EDGE_BLOCK) {
        int4 nd = b4[i];
        atomicOr(&sflags[nd.x >> 4], 1u << ((nd.x & 15) * 2));
        atomicOr(&sflags[nd.y >> 4], 1u << ((nd.y & 15) * 2));
        atomicOr(&sflags[nd.z >> 4], 1u << ((nd.z & 15) * 2));
        atomicOr(&sflags[nd.w >> 4], 1u << ((nd.w & 15) * 2));
    }
    for (int i = (n_bkd4 << 2) + threadIdx.x; i < n_bkd; i += EDGE_BLOCK) {
        int node = bkd_nodes[i];
        atomicOr(&sflags[node >> 4], 1u << ((node & 15) * 2));
    }
    __syncthreads();

    // ---- scan: EPT edges/thread ----
    const int lane = threadIdx.x & 63;
    const int base = (blockIdx.x * EDGE_BLOCK + threadIdx.x) * EPT;
    const int wave_base = (blockIdx.x * EDGE_BLOCK + (threadIdx.x & ~63)) * EPT;
    const bool full = (wave_base + 64 * EPT <= E) && ((E & 3) == 0);

    int us[EPT], vs[EPT];
    if (full) {
        const int4* up = reinterpret_cast<const int4*>(edge_index + base);
        const int4* vp = reinterpret_cast<const int4*>(edge_index + E + base);
        #pragma unroll
        for (int q = 0; q < EPT / 4; ++q) {
            int4 uq = up[q];
            int4 vq = vp[q];
            us[q*4+0] = uq.x; us[q*4+1] = uq.y; us[q*4+2] = uq.z; us[q*4+3] = uq.w;
            vs[q*4+0] = vq.x; vs[q*4+1] = vq.y; vs[q*4+2] = vq.z; vs[q*4+3] = vq.w;
        }
    } else {
        #pragma unroll
        for (int k = 0; k < EPT; ++k) {
            int e = base + k;
            bool ok = (e < E);
            us[k] = ok ? edge_index[e] : 0;
            vs[k] = ok ? edge_index[E + e] : 0;
        }
    }

    float wval = 0.0f;   // accumulated on lane 0 only

    #pragma unroll
    for (int k = 0; k < EPT; ++k) {
        bool valid = full || (base + k < E);
        unsigned fu = (sflags[us[k] >> 4] >> ((us[k] & 15) * 2)) & 3u;
        unsigned fv = (sflags[vs[k] >> 4] >> ((vs[k] & 15) * 2)) & 3u;
        bool m = valid && ((((fu & (fv >> 1)) | (fv & (fu >> 1))) & 1u) != 0);

        unsigned long long mb = __ballot(m);
        while (mb) {
            int b = __ffsll(mb) - 1;
            mb &= mb - 1;
            int eu = __shfl(us[k], b, 64);
            int ev = __shfl(vs[k], b, 64);
            int e_b = wave_base + b * EPT + k;
            float w = edge_weights[e_b];          // uniform address -> broadcast
            if (w != 0.0f) {
                float2 a = reinterpret_cast<const float2*>(x + (size_t)eu * D_FEAT)[lane];
                float2 c = reinterpret_cast<const float2*>(x + (size_t)ev * D_FEAT)[lane];
                float d  = a.x * c.x + a.y * c.y;
                float p  = a.x * a.x + a.y * a.y;
                float q  = c.x * c.x + c.y * c.y;
                #pragma unroll
                for (int off = 1; off < 64; off <<= 1) {
                    d += __shfl_xor(d, off, 64);
                    p += __shfl_xor(p, off, 64);
                    q += __shfl_xor(q, off, 64);
                }
                float nu = fmaxf(sqrtf(p), COS_EPS);
                float nv = fmaxf(sqrtf(q), COS_EPS);
                float term = fmaxf(HOMO_BOOST_THRD - d / (nu * nv), 0.0f);
                if (lane == 0) wval += term;
            }
        }
    }

    if (lane == 0)
        partials[blockIdx.x * (EDGE_BLOCK / 64) + (threadIdx.x >> 6)] = wval;
}

__global__ void reduce_kernel(const float* __restrict__ partials, int n,
                              float* __restrict__ out) {
    __shared__ float wsum[16];
    float s = 0.0f;
    for (int i = threadIdx.x; i < n; i += blockDim.x) s += partials[i];
    #pragma unroll
    for (int off = 32; off > 0; off >>= 1) s += __shfl_down(s, off, 64);
    if ((threadIdx.x & 63) == 0) wsum[threadIdx.x >> 6] = s;
    __syncthreads();
    if (threadIdx.x == 0) {
        float t = 0.0f;
        for (int w = 0; w < (int)(blockDim.x >> 6); ++w) t += wsum[w];
        out[0] = t * HOMO_LOSS_WEIGHT;
    }
}

extern "C" void kernel_launch(void* const* d_in, const int* in_sizes, int n_in,
                              void* d_out, int out_size, void* d_ws, size_t ws_size,
                              hipStream_t stream) {
    const int*   edge_index   = (const int*)  d_in[0];
    const float* edge_weights = (const float*)d_in[1];
    const float* x            = (const float*)d_in[2];
    const int*   target_nodes = (const int*)  d_in[3];
    const int*   bkd_nodes    = (const int*)  d_in[4];

    const int E     = in_sizes[0] / 2;
    const int N     = in_sizes[2] / D_FEAT;
    const int n_tgt = in_sizes[3];
    const int n_bkd = in_sizes[4];

    const int nwords = (N + 15) / 16;
    float* partials = (float*)d_ws;

    const int nblocks = (E + EDGE_BLOCK * EPT - 1) / (EDGE_BLOCK * EPT);
    edge_loss_kernel<<<nblocks, EDGE_BLOCK, 0, stream>>>(
        edge_index, edge_weights, x, target_nodes, n_tgt, bkd_nodes, n_bkd,
        partials, E, nwords);

    const int nwaves = nblocks * (EDGE_BLOCK / 64);
    reduce_kernel<<<1, 1024, 0, stream>>>(partials, nwaves, (float*)d_out);
}

// Round 9
// 13.576 us; speedup vs baseline: 3.6883x; 1.0992x over previous
//
#include <hip/hip_runtime.h>

#define HOMO_BOOST_THRD 0.5f
#define HOMO_LOSS_WEIGHT 100.0f
#define COS_EPS 1e-8f
#define D_FEAT 128
#define EDGE_BLOCK 256
#define EPT 8
#define QMAX (EDGE_BLOCK * EPT)     // max possible matches per block (no overflow)

#define FLAG_WORDS_MAX 4096         // 2 bits/node -> up to 65536 nodes (16 KB LDS)

// Single hot kernel:
//   1) per-block packed 2-bit LDS flag table (bit0=bkd, bit1=tgt), vectorized build
//   2) scan EPT edges/thread (int4 loads); matched+nonzero-weight edges enqueued
//      into an LDS queue (discovery decoupled from processing)
//   3) all 4 waves drain the queue, 2 edges/wave/round, wave-cooperative cosine
// No global atomics/fences anywhere.
__global__ __launch_bounds__(EDGE_BLOCK) void edge_loss_kernel(
        const int* __restrict__ edge_index,        // [2*E]
        const float* __restrict__ edge_weights,    // [E]
        const float* __restrict__ x,               // [N,128]
        const int* __restrict__ target_nodes, int n_tgt,
        const int* __restrict__ bkd_nodes, int n_bkd,
        float* __restrict__ partials, int E, int nwords) {
    __shared__ unsigned int sflags[FLAG_WORDS_MAX];
    __shared__ int q_u[QMAX];
    __shared__ int q_v[QMAX];
    __shared__ int qn;
    __shared__ float wsum[EDGE_BLOCK / 64];

    // ---- prologue: build flag table (vectorized) ----
    uint4* s4 = reinterpret_cast<uint4*>(sflags);
    const int nwords4 = (nwords + 3) >> 2;
    for (int i = threadIdx.x; i < nwords4; i += EDGE_BLOCK)
        s4[i] = make_uint4(0u, 0u, 0u, 0u);
    if (threadIdx.x == 0) qn = 0;
    __syncthreads();

    const int n_tgt4 = n_tgt >> 2;
    const int4* t4 = reinterpret_cast<const int4*>(target_nodes);
    for (int i = threadIdx.x; i < n_tgt4; i += EDGE_BLOCK) {
        int4 nd = t4[i];
        atomicOr(&sflags[nd.x >> 4], 2u << ((nd.x & 15) * 2));
        atomicOr(&sflags[nd.y >> 4], 2u << ((nd.y & 15) * 2));
        atomicOr(&sflags[nd.z >> 4], 2u << ((nd.z & 15) * 2));
        atomicOr(&sflags[nd.w >> 4], 2u << ((nd.w & 15) * 2));
    }
    for (int i = (n_tgt4 << 2) + threadIdx.x; i < n_tgt; i += EDGE_BLOCK) {
        int node = target_nodes[i];
        atomicOr(&sflags[node >> 4], 2u << ((node & 15) * 2));
    }
    const int n_bkd4 = n_bkd >> 2;
    const int4* b4 = reinterpret_cast<const int4*>(bkd_nodes);
    for (int i = threadIdx.x; i < n_bkd4; i += EDGE_BLOCK) {
        int4 nd = b4[i];
        atomicOr(&sflags[nd.x >> 4], 1u << ((nd.x & 15) * 2));
        atomicOr(&sflags[nd.y >> 4], 1u << ((nd.y & 15) * 2));
        atomicOr(&sflags[nd.z >> 4], 1u << ((nd.z & 15) * 2));
        atomicOr(&sflags[nd.w >> 4], 1u << ((nd.w & 15) * 2));
    }
    for (int i = (n_bkd4 << 2) + threadIdx.x; i < n_bkd; i += EDGE_BLOCK) {
        int node = bkd_nodes[i];
        atomicOr(&sflags[node >> 4], 1u << ((node & 15) * 2));
    }
    __syncthreads();

    // ---- scan: EPT edges/thread; enqueue matches ----
    const int base = (blockIdx.x * EDGE_BLOCK + threadIdx.x) * EPT;
    const bool full = (blockIdx.x * EDGE_BLOCK * EPT + EDGE_BLOCK * EPT <= E)
                      && ((E & 3) == 0);

    int us[EPT], vs[EPT];
    if (full) {
        const int4* up = reinterpret_cast<const int4*>(edge_index + base);
        const int4* vp = reinterpret_cast<const int4*>(edge_index + E + base);
        #pragma unroll
        for (int qd = 0; qd < EPT / 4; ++qd) {
            int4 uq = up[qd];
            int4 vq = vp[qd];
            us[qd*4+0] = uq.x; us[qd*4+1] = uq.y; us[qd*4+2] = uq.z; us[qd*4+3] = uq.w;
            vs[qd*4+0] = vq.x; vs[qd*4+1] = vq.y; vs[qd*4+2] = vq.z; vs[qd*4+3] = vq.w;
        }
    } else {
        #pragma unroll
        for (int k = 0; k < EPT; ++k) {
            int e = base + k;
            bool ok = (e < E);
            us[k] = ok ? edge_index[e] : 0;
            vs[k] = ok ? edge_index[E + e] : 0;
        }
    }

    #pragma unroll
    for (int k = 0; k < EPT; ++k) {
        bool valid = full || (base + k < E);
        unsigned fu = (sflags[us[k] >> 4] >> ((us[k] & 15) * 2)) & 3u;
        unsigned fv = (sflags[vs[k] >> 4] >> ((vs[k] & 15) * 2)) & 3u;
        bool m = valid && ((((fu & (fv >> 1)) | (fv & (fu >> 1))) & 1u) != 0);
        if (m) {
            float w = edge_weights[base + k];   // rare predicated load
            if (w != 0.0f) {
                int qi = atomicAdd(&qn, 1);
                q_u[qi] = us[k];
                q_v[qi] = vs[k];
            }
        }
    }
    __syncthreads();

    // ---- drain queue: 2 edges per wave per round (balanced across 4 waves) ----
    const int lane = threadIdx.x & 63;
    const int wid  = threadIdx.x >> 6;
    const int nq   = qn;
    float wval = 0.0f;   // lane 0 of each wave accumulates

    for (int i = wid * 2; i < nq; i += 2 * (EDGE_BLOCK / 64)) {
        bool has1 = (i + 1 < nq);
        int u0 = q_u[i], v0 = q_v[i];
        int u1 = has1 ? q_u[i + 1] : u0;
        int v1 = has1 ? q_v[i + 1] : v0;

        // both edges' row loads issued concurrently (one latency round)
        float2 a0 = reinterpret_cast<const float2*>(x + (size_t)u0 * D_FEAT)[lane];
        float2 c0 = reinterpret_cast<const float2*>(x + (size_t)v0 * D_FEAT)[lane];
        float2 a1 = reinterpret_cast<const float2*>(x + (size_t)u1 * D_FEAT)[lane];
        float2 c1 = reinterpret_cast<const float2*>(x + (size_t)v1 * D_FEAT)[lane];

        float d0 = a0.x * c0.x + a0.y * c0.y;
        float p0 = a0.x * a0.x + a0.y * a0.y;
        float q0 = c0.x * c0.x + c0.y * c0.y;
        float d1 = a1.x * c1.x + a1.y * c1.y;
        float p1 = a1.x * a1.x + a1.y * a1.y;
        float q1 = c1.x * c1.x + c1.y * c1.y;
        #pragma unroll
        for (int off = 1; off < 64; off <<= 1) {
            d0 += __shfl_xor(d0, off, 64);
            p0 += __shfl_xor(p0, off, 64);
            q0 += __shfl_xor(q0, off, 64);
            d1 += __shfl_xor(d1, off, 64);
            p1 += __shfl_xor(p1, off, 64);
            q1 += __shfl_xor(q1, off, 64);
        }
        if (lane == 0) {
            float nu0 = fmaxf(sqrtf(p0), COS_EPS);
            float nv0 = fmaxf(sqrtf(q0), COS_EPS);
            wval += fmaxf(HOMO_BOOST_THRD - d0 / (nu0 * nv0), 0.0f);
            if (has1) {
                float nu1 = fmaxf(sqrtf(p1), COS_EPS);
                float nv1 = fmaxf(sqrtf(q1), COS_EPS);
                wval += fmaxf(HOMO_BOOST_THRD - d1 / (nu1 * nv1), 0.0f);
            }
        }
    }

    if (lane == 0) wsum[wid] = wval;
    __syncthreads();
    if (threadIdx.x == 0)
        partials[blockIdx.x] = wsum[0] + wsum[1] + wsum[2] + wsum[3];
}

__global__ void reduce_kernel(const float* __restrict__ partials, int n,
                              float* __restrict__ out) {
    __shared__ float wsum[16];
    float s = 0.0f;
    for (int i = threadIdx.x; i < n; i += blockDim.x) s += partials[i];
    #pragma unroll
    for (int off = 32; off > 0; off >>= 1) s += __shfl_down(s, off, 64);
    if ((threadIdx.x & 63) == 0) wsum[threadIdx.x >> 6] = s;
    __syncthreads();
    if (threadIdx.x == 0) {
        float t = 0.0f;
        for (int w = 0; w < (int)(blockDim.x >> 6); ++w) t += wsum[w];
        out[0] = t * HOMO_LOSS_WEIGHT;
    }
}

extern "C" void kernel_launch(void* const* d_in, const int* in_sizes, int n_in,
                              void* d_out, int out_size, void* d_ws, size_t ws_size,
                              hipStream_t stream) {
    const int*   edge_index   = (const int*)  d_in[0];
    const float* edge_weights = (const float*)d_in[1];
    const float* x            = (const float*)d_in[2];
    const int*   target_nodes = (const int*)  d_in[3];
    const int*   bkd_nodes    = (const int*)  d_in[4];

    const int E     = in_sizes[0] / 2;
    const int N     = in_sizes[2] / D_FEAT;
    const int n_tgt = in_sizes[3];
    const int n_bkd = in_sizes[4];

    const int nwords = (N + 15) / 16;
    float* partials = (float*)d_ws;

    const int nblocks = (E + EDGE_BLOCK * EPT - 1) / (EDGE_BLOCK * EPT);
    edge_loss_kernel<<<nblocks, EDGE_BLOCK, 0, stream>>>(
        edge_index, edge_weights, x, target_nodes, n_tgt, bkd_nodes, n_bkd,
        partials, E, nwords);

    reduce_kernel<<<1, 1024, 0, stream>>>(partials, nblocks, (float*)d_out);
}